// Round 9
// baseline (164.029 us; speedup 1.0000x reference)
//
#include <hip/hip_runtime.h>
#include <hip/hip_bf16.h>
#include <stdint.h>

// out[8192,4096] = x[8192,2048] @ WeffT^T ; WeffT built from W (4096,2048).
#define M_DIM 8192
#define K_DIM 2048
#define N_DIM 4096
#define BM 256
#define BN 256
#define BK 64
#define NT (K_DIM / BK)    // 32 K-tiles
#define NITER (NT / 2)     // 16 iterations, 2 K-tiles each

typedef __attribute__((ext_vector_type(8))) short bf16x8;
typedef __attribute__((ext_vector_type(4))) float f32x4;

__device__ __forceinline__ unsigned short f2bfu(float f) {
    __hip_bfloat16 h = __float2bfloat16(f);
    return __builtin_bit_cast(unsigned short, h);
}

// ---------------------------------------------------------------------------
// Fused prep (one dispatch), unchanged from R6 (proven):
//   blocks [0, 2048):  WeffT rows {2b, 2b+1} (paired streams)
//   blocks [2048, 2048+16384): x fp32 -> bf16
// ---------------------------------------------------------------------------
__global__ __launch_bounds__(256) void prep_fused(const float* __restrict__ x,
                                                  const float* __restrict__ W,
                                                  unsigned short* __restrict__ xb,
                                                  unsigned short* __restrict__ wt) {
    const int bid = blockIdx.x;
    if (bid < N_DIM / 2) {
        __shared__ float row0[K_DIM];
        __shared__ float row1[K_DIM];
        const int o0 = bid * 2;
        const float* w0 = W + (size_t)o0 * K_DIM;
        const float* w1 = W + (size_t)(o0 + 1) * K_DIM;
#pragma unroll
        for (int t = 0; t < 2; ++t) {
            ((float4*)row0)[threadIdx.x + 256 * t] = ((const float4*)w0)[threadIdx.x + 256 * t];
            ((float4*)row1)[threadIdx.x + 256 * t] = ((const float4*)w1)[threadIdx.x + 256 * t];
        }
        __syncthreads();

        const float* rF0 = W + (size_t)(N_DIM - 1 - o0) * K_DIM;
        const float* rF1 = W + (size_t)(N_DIM - 2 - o0) * K_DIM;
        const float* rm1 = W + (size_t)((o0 - 1) & (N_DIM - 1)) * K_DIM;
        const float* rm2 = W + (size_t)((o0 - 2) & (N_DIM - 1)) * K_DIM;
        const float* rm3 = W + (size_t)((o0 - 3) & (N_DIM - 1)) * K_DIM;
        const float* rm4 = W + (size_t)((o0 - 4) & (N_DIM - 1)) * K_DIM;
        const float* rm5 = W + (size_t)((o0 - 5) & (N_DIM - 1)) * K_DIM;
        unsigned short* wo0 = wt + (size_t)o0 * K_DIM;
        unsigned short* wo1 = wo0 + K_DIM;

#pragma unroll
        for (int t = 0; t < 2; ++t) {
            const int i0 = (threadIdx.x + 256 * t) * 4;
            const float4 vF0 = *(const float4*)(rF0 + i0);
            const float4 vF1 = *(const float4*)(rF1 + i0);
            const float4 v1  = *(const float4*)(rm1 + i0);
            const float4 v2  = *(const float4*)(rm2 + i0);
            const float4 v3  = *(const float4*)(rm3 + i0);
            const float4 v4  = *(const float4*)(rm4 + i0);
            const float4 v5  = *(const float4*)(rm5 + i0);
            ushort4 ov0, ov1;
#pragma unroll
            for (int j = 0; j < 4; ++j) {
                const int i = i0 + j;
                float s0 = row0[i] + row0[K_DIM - 1 - i]
                         + row0[(i - 1) & (K_DIM - 1)] + row0[(i - 2) & (K_DIM - 1)]
                         + row0[(i - 3) & (K_DIM - 1)] + row0[(i - 4) & (K_DIM - 1)]
                         + row0[(i - 5) & (K_DIM - 1)];
                s0 += (&vF0.x)[j] + (&v1.x)[j] + (&v2.x)[j]
                    + (&v3.x)[j] + (&v4.x)[j] + (&v5.x)[j];
                (&ov0.x)[j] = f2bfu(s0);

                float s1 = row1[i] + row1[K_DIM - 1 - i]
                         + row1[(i - 1) & (K_DIM - 1)] + row1[(i - 2) & (K_DIM - 1)]
                         + row1[(i - 3) & (K_DIM - 1)] + row1[(i - 4) & (K_DIM - 1)]
                         + row1[(i - 5) & (K_DIM - 1)];
                s1 += (&vF1.x)[j] + row0[i] + (&v1.x)[j] + (&v2.x)[j]
                    + (&v3.x)[j] + (&v4.x)[j];
                (&ov1.x)[j] = f2bfu(s1);
            }
            *(ushort4*)(wo0 + i0) = ov0;
            *(ushort4*)(wo1 + i0) = ov1;
        }
    } else {
        const int idx = (bid - N_DIM / 2) * 256 + threadIdx.x;
        float4 v = ((const float4*)x)[idx];
        ushort4 o;
        o.x = f2bfu(v.x); o.y = f2bfu(v.y); o.z = f2bfu(v.z); o.w = f2bfu(v.w);
        ((ushort4*)xb)[idx] = o;
    }
}

// ---------------------------------------------------------------------------
// GEMM R9: persistent 2-tile blocks (grid 256; tiles wg and wg+256, same bn0),
// R6 K-loop core + staggered lgkmcnt (6/4/2/0) in the B-loading phases.
//
// LDS per buffer p (64 KiB @ p*65536): A @0 (A0 rows0-127, A1 @16384),
// B @32768 (B0, B1 @49152). Row=128B=8x16B slots, physical slot =
// logical ^ (row&7), both-sides swizzle (rule #21). Proven 0 conflicts.
//
// Stage ledger (per tile, steady state) — unchanged from R6:
//   ph1: t1.A1->buf1   ph2: t2.B0->buf0   ph3: t2.B1->buf0
//   ph4: t2.A0->buf0 + vmcnt(6)
//   ph5: t2.A1->buf0   ph6: t3.B0->buf1   ph7: t3.B1->buf1
//   ph8: t3.A0->buf1 + vmcnt(6)
// Prologue: t0.{B0,B1,A0,A1}, t1.{B0,B1,A0} + vmcnt(6). Last iter: ph4
// vmcnt(0), stages of t>=NT guarded out -> queue empty at tile end.
//
// Tile handoff: tile0 K-loop ends (LDS reads drained, queue empty) ->
// tile1 prologue stages -> vmcnt(6)+barrier -> tile0 C-stores issued
// (drain under tile1 ph1-4; forced by ph4's vmcnt(6)) -> acc re-zero ->
// tile1 K-loop -> tile1 stores.
//
// Staggered lgkm (ph1/ph5 only): reads pinned in groups [a x4 + b0][b1][b2][b3]
// via sched_barrier(0); MFMA fn-outer with lgkmcnt(6/4/2/0) before each
// fn-cluster (ledger: at each wait the needed group is among oldest-done).
// ---------------------------------------------------------------------------
__global__ __launch_bounds__(512, 2) void gemm8p(const unsigned short* __restrict__ Ab,
                                                 const unsigned short* __restrict__ Bt,
                                                 float* __restrict__ C) {
    __shared__ __align__(16) char smem[2 * 65536];

    const int tid  = threadIdx.x;
    const int wave = tid >> 6;
    const int lane = tid & 63;

    // XCD-bijective swizzle (nwg = 256, % 8 == 0)
    const int cpx = 256 >> 3;
    const int wg  = ((int)blockIdx.x & 7) * cpx + ((int)blockIdx.x >> 3);

    const int wr = wave >> 2;                   // 0..1 (M)
    const int wc = wave & 3;                    // 0..3 (N)

    const int srow = tid >> 3;                          // staging row within 64-row chunk
    const int lsw  = (lane & 7) ^ ((lane >> 3) & 7);    // pre-swizzled logical slot

    // ---- ds_read addressing (swizzled; conflict-free, proven R3/R5/R6) ----
    const int r16  = lane & 15;
    const int x7   = lane & 7;
    const int ksl0 = (((lane >> 4)    ) ^ x7) * 16;     // kk=0 slot
    const int ksl1 = (((lane >> 4) | 4) ^ x7) * 16;     // kk=1 slot
    const int aRow = (wr * 128 + r16) * 128;            // byte offset, A region
    const int bRow = (wc * 64  + r16) * 128 + 32768;    // byte offset, B region
    const int crow = (lane >> 4) * 4;
    const int ccol = lane & 15;

    f32x4  acc[8][4];
    bf16x8 b[4][2];
    const unsigned short* gA0;
    const unsigned short* gB0;

#define STAGE_HALF(gbase, opoff, h, t, p) do {                                              \
    char* lds_ = smem + (p) * 65536 + (opoff) + (h) * 16384 + wave * 1024;                  \
    const unsigned short* g_ = (gbase) + (size_t)((h) * 128) * K_DIM + (t) * BK;            \
    __builtin_amdgcn_global_load_lds(                                                        \
        (const __attribute__((address_space(1))) unsigned int*)g_,                           \
        (__attribute__((address_space(3))) unsigned int*)lds_, 16, 0, 0);                    \
    __builtin_amdgcn_global_load_lds(                                                        \
        (const __attribute__((address_space(1))) unsigned int*)(g_ + (size_t)64 * K_DIM),    \
        (__attribute__((address_space(3))) unsigned int*)(lds_ + 8192), 16, 0, 0);           \
} while (0)

// non-B phase: 4 a-reads, full drain (unchanged from R6)
#define PHASE(P, Q, STAGE_STMT, VM_STMT) do {                                               \
    const char* base_ = smem + (P) * 65536;                                                 \
    bf16x8 a_[2][2];                                                                        \
    a_[0][0] = *(const bf16x8*)(base_ + aRow + (Q) * 4096 + ksl0);                          \
    a_[0][1] = *(const bf16x8*)(base_ + aRow + (Q) * 4096 + ksl1);                          \
    a_[1][0] = *(const bf16x8*)(base_ + aRow + (Q) * 4096 + 2048 + ksl0);                   \
    a_[1][1] = *(const bf16x8*)(base_ + aRow + (Q) * 4096 + 2048 + ksl1);                   \
    STAGE_STMT;                                                                             \
    __builtin_amdgcn_s_barrier();                                                           \
    asm volatile("s_waitcnt lgkmcnt(0)" ::: "memory");                                      \
    __builtin_amdgcn_sched_barrier(0);                                                      \
    __builtin_amdgcn_s_setprio(1);                                                          \
    _Pragma("unroll")                                                                       \
    for (int fm = 0; fm < 2; ++fm)                                                          \
        _Pragma("unroll")                                                                   \
        for (int fn = 0; fn < 4; ++fn) {                                                    \
            acc[(Q)*2 + fm][fn] = __builtin_amdgcn_mfma_f32_16x16x32_bf16(                  \
                a_[fm][0], b[fn][0], acc[(Q)*2 + fm][fn], 0, 0, 0);                         \
            acc[(Q)*2 + fm][fn] = __builtin_amdgcn_mfma_f32_16x16x32_bf16(                  \
                a_[fm][1], b[fn][1], acc[(Q)*2 + fm][fn], 0, 0, 0);                         \
        }                                                                                   \
    __builtin_amdgcn_s_setprio(0);                                                          \
    VM_STMT;                                                                                \
    __builtin_amdgcn_s_barrier();                                                           \
} while (0)

// one fn-cluster: 4 MFMA (fm0,fm1 x kk0,kk1)
#define FN_CLUSTER(Q, FN) do {                                                              \
    _Pragma("unroll")                                                                       \
    for (int fm = 0; fm < 2; ++fm) {                                                        \
        acc[(Q)*2 + fm][FN] = __builtin_amdgcn_mfma_f32_16x16x32_bf16(                      \
            a_[fm][0], b[FN][0], acc[(Q)*2 + fm][FN], 0, 0, 0);                             \
        acc[(Q)*2 + fm][FN] = __builtin_amdgcn_mfma_f32_16x16x32_bf16(                      \
            a_[fm][1], b[FN][1], acc[(Q)*2 + fm][FN], 0, 0, 0);                             \
    }                                                                                       \
} while (0)

// B-loading phase (ph1/ph5): staggered lgkm 6/4/2/0, fn-outer MFMA
#define PHASE_B(P, Q, STAGE_STMT, VM_STMT) do {                                             \
    const char* base_ = smem + (P) * 65536;                                                 \
    bf16x8 a_[2][2];                                                                        \
    a_[0][0] = *(const bf16x8*)(base_ + aRow + (Q) * 4096 + ksl0);                          \
    a_[0][1] = *(const bf16x8*)(base_ + aRow + (Q) * 4096 + ksl1);                          \
    a_[1][0] = *(const bf16x8*)(base_ + aRow + (Q) * 4096 + 2048 + ksl0);                   \
    a_[1][1] = *(const bf16x8*)(base_ + aRow + (Q) * 4096 + 2048 + ksl1);                   \
    b[0][0] = *(const bf16x8*)(base_ + bRow + ksl0);                                        \
    b[0][1] = *(const bf16x8*)(base_ + bRow + ksl1);                                        \
    __builtin_amdgcn_sched_barrier(0);                                                      \
    b[1][0] = *(const bf16x8*)(base_ + bRow + 2048 + ksl0);                                 \
    b[1][1] = *(const bf16x8*)(base_ + bRow + 2048 + ksl1);                                 \
    __builtin_amdgcn_sched_barrier(0);                                                      \
    b[2][0] = *(const bf16x8*)(base_ + bRow + 4096 + ksl0);                                 \
    b[2][1] = *(const bf16x8*)(base_ + bRow + 4096 + ksl1);                                 \
    __builtin_amdgcn_sched_barrier(0);                                                      \
    b[3][0] = *(const bf16x8*)(base_ + bRow + 6144 + ksl0);                                 \
    b[3][1] = *(const bf16x8*)(base_ + bRow + 6144 + ksl1);                                 \
    __builtin_amdgcn_sched_barrier(0);                                                      \
    STAGE_STMT;                                                                             \
    __builtin_amdgcn_s_barrier();                                                           \
    asm volatile("s_waitcnt lgkmcnt(6)" ::: "memory");                                      \
    __builtin_amdgcn_sched_barrier(0);                                                      \
    __builtin_amdgcn_s_setprio(1);                                                          \
    FN_CLUSTER(Q, 0);                                                                       \
    __builtin_amdgcn_sched_barrier(0);                                                      \
    asm volatile("s_waitcnt lgkmcnt(4)" ::: "memory");                                      \
    __builtin_amdgcn_sched_barrier(0);                                                      \
    FN_CLUSTER(Q, 1);                                                                       \
    __builtin_amdgcn_sched_barrier(0);                                                      \
    asm volatile("s_waitcnt lgkmcnt(2)" ::: "memory");                                      \
    __builtin_amdgcn_sched_barrier(0);                                                      \
    FN_CLUSTER(Q, 2);                                                                       \
    __builtin_amdgcn_sched_barrier(0);                                                      \
    asm volatile("s_waitcnt lgkmcnt(0)" ::: "memory");                                      \
    __builtin_amdgcn_sched_barrier(0);                                                      \
    FN_CLUSTER(Q, 3);                                                                       \
    __builtin_amdgcn_s_setprio(0);                                                          \
    VM_STMT;                                                                                \
    __builtin_amdgcn_s_barrier();                                                           \
} while (0)

#define PROLOGUE() do {                                                                     \
    STAGE_HALF(gB0, 32768, 0, 0, 0);                                                        \
    STAGE_HALF(gB0, 32768, 1, 0, 0);                                                        \
    STAGE_HALF(gA0, 0,     0, 0, 0);                                                        \
    STAGE_HALF(gA0, 0,     1, 0, 0);                                                        \
    STAGE_HALF(gB0, 32768, 0, 1, 1);                                                        \
    STAGE_HALF(gB0, 32768, 1, 1, 1);                                                        \
    STAGE_HALF(gA0, 0,     0, 1, 1);                                                        \
    asm volatile("s_waitcnt vmcnt(6)" ::: "memory");                                        \
    __builtin_amdgcn_s_barrier();                                                           \
} while (0)

#define KLOOP() do {                                                                        \
    for (int u = 0; u < NITER; ++u) {                                                       \
        const bool last = (u == NITER - 1);                                                 \
        const int  t1 = 2 * u + 1, t2 = 2 * u + 2, t3 = 2 * u + 3;                          \
        PHASE_B(0, 0, { STAGE_HALF(gA0, 0, 1, t1, 1); }, {});                               \
        PHASE(0, 1, { if (!last) STAGE_HALF(gB0, 32768, 0, t2, 0); }, {});                  \
        PHASE(0, 2, { if (!last) STAGE_HALF(gB0, 32768, 1, t2, 0); }, {});                  \
        PHASE(0, 3, { if (!last) STAGE_HALF(gA0, 0, 0, t2, 0); },                           \
              { if (last) asm volatile("s_waitcnt vmcnt(0)" ::: "memory");                  \
                else      asm volatile("s_waitcnt vmcnt(6)" ::: "memory"); });              \
        PHASE_B(1, 0, { if (!last) STAGE_HALF(gA0, 0, 1, t2, 0); }, {});                    \
        PHASE(1, 1, { if (!last) STAGE_HALF(gB0, 32768, 0, t3, 1); }, {});                  \
        PHASE(1, 2, { if (!last) STAGE_HALF(gB0, 32768, 1, t3, 1); }, {});                  \
        PHASE(1, 3, { if (!last) STAGE_HALF(gA0, 0, 0, t3, 1); },                           \
              { if (!last) asm volatile("s_waitcnt vmcnt(6)" ::: "memory"); });             \
    }                                                                                       \
} while (0)

#define CSTORE(Cb) do {                                                                     \
    _Pragma("unroll")                                                                       \
    for (int fm = 0; fm < 8; ++fm)                                                          \
        _Pragma("unroll")                                                                   \
        for (int fn = 0; fn < 4; ++fn)                                                      \
            _Pragma("unroll")                                                               \
            for (int r = 0; r < 4; ++r)                                                     \
                (Cb)[(size_t)(fm * 16 + r) * N_DIM + fn * 16] = acc[fm][fn][r];             \
} while (0)

#define ZERO_ACC() do {                                                                     \
    _Pragma("unroll")                                                                       \
    for (int i_ = 0; i_ < 8; ++i_)                                                          \
        _Pragma("unroll")                                                                   \
        for (int j_ = 0; j_ < 4; ++j_)                                                      \
            acc[i_][j_] = (f32x4){0.f, 0.f, 0.f, 0.f};                                      \
} while (0)

    // ================= tile 0 =================
    int bm0 = (wg >> 4) * BM;
    int bn0 = (wg & 15) * BN;
    gA0 = Ab + (size_t)(bm0 + srow) * K_DIM + lsw * 8;
    gB0 = Bt + (size_t)(bn0 + srow) * K_DIM + lsw * 8;
    float* Cb0 = C + (size_t)(bm0 + wr * 128 + crow) * N_DIM + (bn0 + wc * 64 + ccol);

    PROLOGUE();
    ZERO_ACC();
    KLOOP();

    // ================= tile 1 (same bn0, bm0 += 4096; B-panel L2-warm) =====
    bm0 += 4096;
    gA0 = Ab + (size_t)(bm0 + srow) * K_DIM + lsw * 8;
    float* Cb1 = C + (size_t)(bm0 + wr * 128 + crow) * N_DIM + (bn0 + wc * 64 + ccol);

    PROLOGUE();          // LDS free (tile0 drained); queue was empty -> vmcnt(6) clean
    CSTORE(Cb0);         // tile0 stores drain under tile1 ph1-4 (forced by ph4 vmcnt)
    ZERO_ACC();          // WAR on acc: ordered after stores by data dependence
    KLOOP();
    CSTORE(Cb1);

#undef CSTORE
#undef ZERO_ACC
#undef KLOOP
#undef PROLOGUE
#undef PHASE_B
#undef FN_CLUSTER
#undef PHASE
#undef STAGE_HALF
}

// ---------------------------------------------------------------------------
extern "C" void kernel_launch(void* const* d_in, const int* in_sizes, int n_in,
                              void* d_out, int out_size, void* d_ws, size_t ws_size,
                              hipStream_t stream) {
    const float* x = (const float*)d_in[0];   // (4,2048,2048) fp32
    const float* W = (const float*)d_in[1];   // (4096,2048) fp32
    float* out = (float*)d_out;               // (4,2048,4096) fp32

    unsigned short* xb = (unsigned short*)d_ws;                                      // 32 MB bf16 x
    unsigned short* wt = (unsigned short*)((char*)d_ws + (size_t)M_DIM * K_DIM * 2); // 16 MB WeffT

    const int cvt_blocks = (M_DIM * K_DIM) / 4 / 256;   // 16384
    prep_fused<<<N_DIM / 2 + cvt_blocks, 256, 0, stream>>>(x, W, xb, wt);

    gemm8p<<<256, 512, 0, stream>>>(xb, wt, out);       // persistent: 2 tiles/block
}